// Round 1
// baseline (471.864 us; speedup 1.0000x reference)
//
#include <hip/hip_runtime.h>
#include <hip/hip_bf16.h>

// Problem constants (fixed by the reference)
#define NN   50000   // nodes
#define FF   512     // input features
#define DD   128     // embedding dim
#define CC   128     // conv channels
#define EE   20000   // hyperedges
#define MM   8       // nodes per hyperedge
#define EPSV 1e-5f

typedef __attribute__((ext_vector_type(8))) short bfrag;   // 8 bf16 (4 VGPRs)
typedef __attribute__((ext_vector_type(4))) float f32x4;   // MFMA accumulator

// fp32 -> bf16 bits, round-to-nearest-even
__device__ __forceinline__ unsigned short f2bf(float f) {
    unsigned u = __builtin_bit_cast(unsigned, f);
    unsigned r = u + 0x7FFFu + ((u >> 16) & 1u);
    return (unsigned short)(r >> 16);
}
__device__ __forceinline__ float bf2f(unsigned short h) {
    unsigned u = ((unsigned)h) << 16;
    return __builtin_bit_cast(float, u);
}
// split a into hi+lo bf16 (residual split: a ~= hi + lo, error ~2^-17 |a|)
__device__ __forceinline__ void split1(float a, short& hi, short& lo) {
    unsigned short h = f2bf(a);
    hi = (short)h;
    lo = (short)f2bf(a - bf2f(h));
}

// ---------------------------------------------------------------------------
// K0: prep — transposed, hi/lo-split bf16 weights.
//   WencT[n][k] = W_enc[k][n]                       (128 x 512)
//   WabT [c][k] : k<128 -> Wa[k][c], k>=128 -> Wb[k-128][c]   (128 x 256)
//   Wa = W0 + W1/7 - (47/49) W2 ;  Wb = -W1/7 + (12/49) W2
// ---------------------------------------------------------------------------
__global__ void prep_kernel(const float* __restrict__ W_enc,
                            const float* __restrict__ cheb_W,
                            unsigned short* __restrict__ WencT_hi,
                            unsigned short* __restrict__ WencT_lo,
                            unsigned short* __restrict__ WabT_hi,
                            unsigned short* __restrict__ WabT_lo) {
    int tid = blockIdx.x * blockDim.x + threadIdx.x;
    int stride = gridDim.x * blockDim.x;
    for (int idx = tid; idx < DD * FF; idx += stride) {
        int n = idx / FF, k = idx % FF;
        float v = W_enc[k * DD + n];
        short hi, lo; split1(v, hi, lo);
        WencT_hi[idx] = (unsigned short)hi;
        WencT_lo[idx] = (unsigned short)lo;
    }
    const float c1 = 1.0f / 7.0f;        // W1 coeff in Wa
    const float c2 = -47.0f / 49.0f;     // W2 coeff in Wa
    const float c3 = -1.0f / 7.0f;       // W1 coeff in Wb
    const float c4 = 12.0f / 49.0f;      // W2 coeff in Wb
    for (int idx = tid; idx < DD * 256; idx += stride) {
        int c = idx / 256, k = idx % 256;
        float v;
        if (k < DD) {
            v = cheb_W[0 * DD * CC + k * CC + c]
              + c1 * cheb_W[1 * DD * CC + k * CC + c]
              + c2 * cheb_W[2 * DD * CC + k * CC + c];
        } else {
            int d = k - DD;
            v = c3 * cheb_W[1 * DD * CC + d * CC + c]
              + c4 * cheb_W[2 * DD * CC + d * CC + c];
        }
        short hi, lo; split1(v, hi, lo);
        WabT_hi[idx] = (unsigned short)hi;
        WabT_lo[idx] = (unsigned short)lo;
    }
}

// ---------------------------------------------------------------------------
// K1: encoder GEMM  x = clip(pos @ W_enc + b_enc, -1, 1)   [50000,128] fp32
// BM=64 (4 waves x 16-row m-tile), BN=128 (8 n-tiles), K=512.
// A read directly from global fp32 and hi/lo-split in registers.
// 3-pass split MFMA: hi*hi + hi*lo + lo*hi.
// ---------------------------------------------------------------------------
__global__ __launch_bounds__(256) void enc_kernel(
        const float* __restrict__ pos,
        const unsigned short* __restrict__ BT_hi,
        const unsigned short* __restrict__ BT_lo,
        const float* __restrict__ b_enc,
        float* __restrict__ x) {
    const int w   = threadIdx.x >> 6;
    const int l   = threadIdx.x & 63;
    const int l15 = l & 15;
    const int lg  = l >> 4;

    const int arow = blockIdx.x * 64 + w * 16 + l15;     // A-fragment row
    const long arow_c = (arow < NN) ? (long)arow : 0;    // clamp for guard rows
    const float* aBase = pos + arow_c * FF + lg * 8;

    f32x4 acc[8];
#pragma unroll
    for (int i = 0; i < 8; i++) acc[i] = (f32x4){0.f, 0.f, 0.f, 0.f};

    for (int ks = 0; ks < FF / 32; ks++) {
        const float* ap = aBase + ks * 32;
        float4 a0 = *(const float4*)(ap);
        float4 a1 = *(const float4*)(ap + 4);
        float av[8] = {a0.x, a0.y, a0.z, a0.w, a1.x, a1.y, a1.z, a1.w};
        bfrag ahi, alo;
#pragma unroll
        for (int j = 0; j < 8; j++) { short h, lo2; split1(av[j], h, lo2); ahi[j] = h; alo[j] = lo2; }

        const int koff = ks * 32 + lg * 8;
#pragma unroll
        for (int nt = 0; nt < 8; nt++) {
            const size_t boff = (size_t)(nt * 16 + l15) * FF + koff;
            bfrag bhi = *(const bfrag*)(BT_hi + boff);
            bfrag blo = *(const bfrag*)(BT_lo + boff);
            acc[nt] = __builtin_amdgcn_mfma_f32_16x16x32_bf16(ahi, bhi, acc[nt], 0, 0, 0);
            acc[nt] = __builtin_amdgcn_mfma_f32_16x16x32_bf16(ahi, blo, acc[nt], 0, 0, 0);
            acc[nt] = __builtin_amdgcn_mfma_f32_16x16x32_bf16(alo, bhi, acc[nt], 0, 0, 0);
        }
    }

    // Epilogue: C/D layout col = lane&15, row = (lane>>4)*4 + q
#pragma unroll
    for (int nt = 0; nt < 8; nt++) {
        const int col = nt * 16 + l15;
        const float bias = b_enc[col];
#pragma unroll
        for (int q = 0; q < 4; q++) {
            const int r = blockIdx.x * 64 + w * 16 + lg * 4 + q;
            if (r < NN) {
                float v = acc[nt][q] + bias;
                v = fminf(1.0f, fmaxf(-1.0f, v));
                x[(long)r * DD + col] = v;
            }
        }
    }
}

// ---------------------------------------------------------------------------
// K3: fused edge kernel. Block = 8 hyperedges (64 incidence rows).
//  Phase 1: gather x rows -> LDS, GraphNorm in LDS, per-edge colsum S.
//  Phase 2: [64,256] @ [256,128] split-bf16 MFMA  (K = 128 norm | 128 S).
//  Phase 3: Hardtanh + pooling (max-min, rms) + linear + sigmoid -> out[e].
// ---------------------------------------------------------------------------
__global__ __launch_bounds__(256) void edge_kernel(
        const float* __restrict__ x,
        const int* __restrict__ members,
        const unsigned short* __restrict__ WabT_hi,
        const unsigned short* __restrict__ WabT_lo,
        const float* __restrict__ gn_gamma,
        const float* __restrict__ gn_beta,
        const float* __restrict__ gn_alpha,
        const float* __restrict__ cheb_b,
        const float* __restrict__ lin_W,
        const float* __restrict__ lin_b,
        float* __restrict__ out) {
    __shared__ float xbuf[64][132];   // normalized rows (pad 4 -> 2-way banks)
    __shared__ float sbuf[8][132];    // per-edge colsum of normalized rows

    const int t = threadIdx.x;
    const int e0 = blockIdx.x * 8;

    // ---- gather: 64 rows x 128 floats, float4 coalesced
    for (int idx = t; idx < 64 * 32; idx += 256) {
        const int r = idx >> 5, c4 = idx & 31;
        const int node = members[(e0 + (r >> 3)) * MM + (r & 7)];
        const float4 v = *(const float4*)(x + (long)node * DD + c4 * 4);
        *(float4*)(&xbuf[r][c4 * 4]) = v;
    }
    __syncthreads();

    // ---- GraphNorm per (edge, feature): stats over the 8 member rows
    for (int p = t; p < 8 * DD; p += 256) {
        const int el = p >> 7, d = p & 127;
        const float a = gn_alpha[d], g = gn_gamma[d], b = gn_beta[d];
        float v[8]; float s = 0.f;
#pragma unroll
        for (int i = 0; i < 8; i++) { v[i] = xbuf[el * 8 + i][d]; s += v[i]; }
        const float m = s * 0.125f;
        float var = 0.f;
#pragma unroll
        for (int i = 0; i < 8; i++) { const float c = v[i] - a * m; v[i] = c; var += c * c; }
        var *= 0.125f;
        const float sc = g * rsqrtf(var + EPSV);
        float S = 0.f;
#pragma unroll
        for (int i = 0; i < 8; i++) { const float nv = sc * v[i] + b; xbuf[el * 8 + i][d] = nv; S += nv; }
        sbuf[el][d] = S;
    }
    __syncthreads();

    // ---- MFMA: rows = wave's 16-row m-tile, K=256 (norm | S), N=128
    const int w   = t >> 6;
    const int l   = t & 63;
    const int l15 = l & 15;
    const int lg  = l >> 4;
    const int arow = w * 16 + l15;       // 0..63
    const int eloc = arow >> 3;          // local edge for the S half

    f32x4 acc[8];
#pragma unroll
    for (int i = 0; i < 8; i++) acc[i] = (f32x4){0.f, 0.f, 0.f, 0.f};

    for (int ks = 0; ks < 8; ks++) {
        const int k = ks * 32 + lg * 8;
        const float* ap = (k < 128) ? &xbuf[arow][k] : &sbuf[eloc][k - 128];
        float4 a0 = *(const float4*)(ap);
        float4 a1 = *(const float4*)(ap + 4);
        float av[8] = {a0.x, a0.y, a0.z, a0.w, a1.x, a1.y, a1.z, a1.w};
        bfrag ahi, alo;
#pragma unroll
        for (int j = 0; j < 8; j++) { short h, lo2; split1(av[j], h, lo2); ahi[j] = h; alo[j] = lo2; }

#pragma unroll
        for (int nt = 0; nt < 8; nt++) {
            const size_t boff = (size_t)(nt * 16 + l15) * 256 + k;
            bfrag bhi = *(const bfrag*)(WabT_hi + boff);
            bfrag blo = *(const bfrag*)(WabT_lo + boff);
            acc[nt] = __builtin_amdgcn_mfma_f32_16x16x32_bf16(ahi, bhi, acc[nt], 0, 0, 0);
            acc[nt] = __builtin_amdgcn_mfma_f32_16x16x32_bf16(ahi, blo, acc[nt], 0, 0, 0);
            acc[nt] = __builtin_amdgcn_mfma_f32_16x16x32_bf16(alo, bhi, acc[nt], 0, 0, 0);
        }
    }

    // ---- epilogue: lane holds rows lg*4+q (within m-tile), col nt*16+l15.
    // rows 0..7 -> edge w*2, rows 8..15 -> edge w*2+1; lane^16 holds other 4 rows.
    float partial = 0.f;
#pragma unroll
    for (int nt = 0; nt < 8; nt++) {
        const int col = nt * 16 + l15;
        const float bias = cheb_b[col];
        float mx = -2.f, mn = 2.f, ssq = 0.f;
#pragma unroll
        for (int q = 0; q < 4; q++) {
            float h = acc[nt][q] + bias;
            h = fminf(1.0f, fmaxf(-1.0f, h));
            mx = fmaxf(mx, h); mn = fminf(mn, h); ssq += h * h;
        }
        mx = fmaxf(mx, __shfl_xor(mx, 16));
        mn = fminf(mn, __shfl_xor(mn, 16));
        ssq += __shfl_xor(ssq, 16);
        const float yr = sqrtf(ssq * 0.125f);
        partial += (mx - mn) * lin_W[col] + yr * lin_W[128 + col];
    }
    if (lg & 1) partial = 0.f;   // drop duplicated lane-groups
    partial += __shfl_xor(partial, 1);
    partial += __shfl_xor(partial, 2);
    partial += __shfl_xor(partial, 4);
    partial += __shfl_xor(partial, 8);
    if (l == 0 || l == 32) {
        const int e = e0 + w * 2 + (l >> 5);
        const float z = partial + lin_b[0];
        out[e] = 1.0f / (1.0f + expf(-z));
    }
}

// ---------------------------------------------------------------------------
extern "C" void kernel_launch(void* const* d_in, const int* in_sizes, int n_in,
                              void* d_out, int out_size, void* d_ws, size_t ws_size,
                              hipStream_t stream) {
    const float* pos    = (const float*)d_in[0];
    const float* W_enc  = (const float*)d_in[1];
    const float* b_enc  = (const float*)d_in[2];
    const float* gammaP = (const float*)d_in[3];
    const float* betaP  = (const float*)d_in[4];
    const float* alphaP = (const float*)d_in[5];
    const float* cheb_W = (const float*)d_in[6];
    const float* cheb_b = (const float*)d_in[7];
    const float* lin_W  = (const float*)d_in[8];
    const float* lin_b  = (const float*)d_in[9];
    const int*   members = (const int*)d_in[10];
    // d_in[11] edge_index, d_in[12] batch: structure is a fixed 8-clique; unused.
    float* out = (float*)d_out;

    char* ws = (char*)d_ws;
    float* x = (float*)ws;                                   // 50000*128*4 = 25,600,000 B
    unsigned short* WencT_hi = (unsigned short*)(ws + 25600000);   // 128*512 shorts
    unsigned short* WencT_lo = WencT_hi + DD * FF;
    unsigned short* WabT_hi  = WencT_lo + DD * FF;           // 128*256 shorts
    unsigned short* WabT_lo  = WabT_hi + DD * 256;

    prep_kernel<<<64, 256, 0, stream>>>(W_enc, cheb_W, WencT_hi, WencT_lo, WabT_hi, WabT_lo);
    enc_kernel<<<(NN + 63) / 64, 256, 0, stream>>>(pos, WencT_hi, WencT_lo, b_enc, x);
    edge_kernel<<<EE / 8, 256, 0, stream>>>(x, members, WabT_hi, WabT_lo,
                                            gammaP, betaP, alphaP, cheb_b, lin_W, lin_b, out);
}

// Round 2
// 266.502 us; speedup vs baseline: 1.7706x; 1.7706x over previous
//
#include <hip/hip_runtime.h>
#include <hip/hip_bf16.h>

// Problem constants (fixed by the reference)
#define NN   50000   // nodes
#define FF   512     // input features
#define DD   128     // embedding dim
#define CC   128     // conv channels
#define EE   20000   // hyperedges
#define MM   8       // nodes per hyperedge
#define EPSV 1e-5f

typedef __attribute__((ext_vector_type(8))) short bfrag;   // 8 bf16 (4 VGPRs)
typedef __attribute__((ext_vector_type(4))) float f32x4;   // MFMA accumulator

// fp32 -> bf16 bits, round-to-nearest-even
__device__ __forceinline__ unsigned short f2bf(float f) {
    unsigned u = __builtin_bit_cast(unsigned, f);
    unsigned r = u + 0x7FFFu + ((u >> 16) & 1u);
    return (unsigned short)(r >> 16);
}
__device__ __forceinline__ float bf2f(unsigned short h) {
    unsigned u = ((unsigned)h) << 16;
    return __builtin_bit_cast(float, u);
}
// split a into hi+lo bf16 (residual split: a ~= hi + lo, error ~2^-17 |a|)
__device__ __forceinline__ void split1(float a, short& hi, short& lo) {
    unsigned short h = f2bf(a);
    hi = (short)h;
    lo = (short)f2bf(a - bf2f(h));
}

// ---------------------------------------------------------------------------
// K0: prep — transposed, hi/lo-split bf16 weights (linear layout; consumers
// swizzle at LDS-write time).
//   WencT[n][k] = W_enc[k][n]                       (128 x 512)
//   WabT [c][k] : k<128 -> Wa[k][c], k>=128 -> Wb[k-128][c]   (128 x 256)
//   Wa = W0 + W1/7 - (47/49) W2 ;  Wb = -W1/7 + (12/49) W2
// ---------------------------------------------------------------------------
__global__ void prep_kernel(const float* __restrict__ W_enc,
                            const float* __restrict__ cheb_W,
                            unsigned short* __restrict__ WencT_hi,
                            unsigned short* __restrict__ WencT_lo,
                            unsigned short* __restrict__ WabT_hi,
                            unsigned short* __restrict__ WabT_lo) {
    int tid = blockIdx.x * blockDim.x + threadIdx.x;
    int stride = gridDim.x * blockDim.x;
    for (int idx = tid; idx < DD * FF; idx += stride) {
        int n = idx / FF, k = idx % FF;
        float v = W_enc[k * DD + n];
        short hi, lo; split1(v, hi, lo);
        WencT_hi[idx] = (unsigned short)hi;
        WencT_lo[idx] = (unsigned short)lo;
    }
    const float c1 = 1.0f / 7.0f;
    const float c2 = -47.0f / 49.0f;
    const float c3 = -1.0f / 7.0f;
    const float c4 = 12.0f / 49.0f;
    for (int idx = tid; idx < DD * 256; idx += stride) {
        int c = idx / 256, k = idx % 256;
        float v;
        if (k < DD) {
            v = cheb_W[0 * DD * CC + k * CC + c]
              + c1 * cheb_W[1 * DD * CC + k * CC + c]
              + c2 * cheb_W[2 * DD * CC + k * CC + c];
        } else {
            int d = k - DD;
            v = c3 * cheb_W[1 * DD * CC + d * CC + c]
              + c4 * cheb_W[2 * DD * CC + d * CC + c];
        }
        short hi, lo; split1(v, hi, lo);
        WabT_hi[idx] = (unsigned short)hi;
        WabT_lo[idx] = (unsigned short)lo;
    }
}

// ---------------------------------------------------------------------------
// K1: encoder GEMM  x = clip(pos @ W_enc + b_enc, -1, 1)   [50000,128] fp32
// 512 threads = 8 waves, BM=128 rows/block, N=128, K in 4 phases of 128.
// B hi/lo tile (64 KB) staged in LDS per phase with XOR slot-swizzle.
// A streamed from global (fp32, split in registers). 2 blocks/CU.
// ---------------------------------------------------------------------------
__global__ __launch_bounds__(512, 4) void enc_kernel(
        const float* __restrict__ pos,
        const unsigned short* __restrict__ BT_hi,
        const unsigned short* __restrict__ BT_lo,
        const float* __restrict__ b_enc,
        float* __restrict__ x) {
    __shared__ unsigned short bsh[2][DD * 128];   // 64 KB, swizzled slots
    const int t = threadIdx.x;
    const int w = t >> 6, l = t & 63, l15 = l & 15, lg = l >> 4;

    const int arow = blockIdx.x * 128 + w * 16 + l15;
    const long arow_c = (arow < NN) ? (long)arow : 0;
    const float* aBase = pos + arow_c * FF + lg * 8;

    f32x4 acc[8];
#pragma unroll
    for (int i = 0; i < 8; i++) acc[i] = (f32x4){0.f, 0.f, 0.f, 0.f};

    for (int ph = 0; ph < 4; ph++) {
        if (ph) __syncthreads();
        // stage B[128 rows][128 k] hi+lo: 4096 16B chunks, swizzled slot
        for (int c = t; c < 4096; c += 512) {
            const int arr = c >> 11, rc = c & 2047, row = rc >> 4, slot = rc & 15;
            const unsigned short* src = (arr ? BT_lo : BT_hi) + row * FF + ph * 128 + slot * 8;
            *(bfrag*)&bsh[arr][row * 128 + ((slot ^ (row & 7)) << 3)] = *(const bfrag*)src;
        }
        __syncthreads();
#pragma unroll
        for (int ks = 0; ks < 4; ks++) {
            const float* ap = aBase + ph * 128 + ks * 32;
            const float4 a0 = *(const float4*)ap;
            const float4 a1 = *(const float4*)(ap + 4);
            const float av[8] = {a0.x, a0.y, a0.z, a0.w, a1.x, a1.y, a1.z, a1.w};
            bfrag ahi, alo;
#pragma unroll
            for (int j = 0; j < 8; j++) { short h, lo2; split1(av[j], h, lo2); ahi[j] = h; alo[j] = lo2; }
            const int sb = ks * 4 + lg;
#pragma unroll
            for (int nt = 0; nt < 8; nt++) {
                const int row = nt * 16 + l15;
                const int off = row * 128 + ((sb ^ (row & 7)) << 3);
                const bfrag bhi = *(const bfrag*)&bsh[0][off];
                const bfrag blo = *(const bfrag*)&bsh[1][off];
                acc[nt] = __builtin_amdgcn_mfma_f32_16x16x32_bf16(ahi, bhi, acc[nt], 0, 0, 0);
                acc[nt] = __builtin_amdgcn_mfma_f32_16x16x32_bf16(ahi, blo, acc[nt], 0, 0, 0);
                acc[nt] = __builtin_amdgcn_mfma_f32_16x16x32_bf16(alo, bhi, acc[nt], 0, 0, 0);
            }
        }
    }

    // Epilogue: C/D layout col = lane&15, row = (lane>>4)*4 + q
#pragma unroll
    for (int nt = 0; nt < 8; nt++) {
        const int col = nt * 16 + l15;
        const float bias = b_enc[col];
#pragma unroll
        for (int q = 0; q < 4; q++) {
            const int r = blockIdx.x * 128 + w * 16 + lg * 4 + q;
            if (r < NN) {
                float v = acc[nt][q] + bias;
                x[(long)r * DD + col] = fminf(1.0f, fmaxf(-1.0f, v));
            }
        }
    }
}

// ---------------------------------------------------------------------------
// K2: fused edge kernel — wave-autonomous (no barriers after B staging).
// 1024 threads = 16 waves, 32 edges/block (2 edges per wave = one 16-row
// m-tile). GraphNorm in registers via shfl over the 8 member rows;
// per-edge colsum closed form S = 8*(sc*m*(1-alpha) + beta).
// B = WabT hi/lo (128 KB) in LDS, XOR slot-swizzled.
// ---------------------------------------------------------------------------
__global__ __launch_bounds__(1024, 4) void edge_kernel(
        const float* __restrict__ x,
        const int* __restrict__ members,
        const unsigned short* __restrict__ WabT_hi,
        const unsigned short* __restrict__ WabT_lo,
        const float* __restrict__ gn_gamma,
        const float* __restrict__ gn_beta,
        const float* __restrict__ gn_alpha,
        const float* __restrict__ cheb_b,
        const float* __restrict__ lin_W,
        const float* __restrict__ lin_b,
        float* __restrict__ out) {
    __shared__ unsigned short bsh[2][DD * 256];   // 128 KB, swizzled slots

    const int t = threadIdx.x;
    const int w = t >> 6, l = t & 63, l15 = l & 15, lg = l >> 4;
    const int e0 = blockIdx.x * 32;

    // ---- stage B once: 8192 16B chunks over 1024 threads
    for (int c = t; c < 8192; c += 1024) {
        const int arr = c >> 12, rc = c & 4095, row = rc >> 5, slot = rc & 31;
        const unsigned short* src = (arr ? WabT_lo : WabT_hi) + row * 256 + slot * 8;
        *(bfrag*)&bsh[arr][row * 256 + ((slot ^ (row & 7)) << 3)] = *(const bfrag*)src;
    }

    // this wave's 2 edges; lane row = l15 (rows 0-7 edge A, 8-15 edge B)
    const int e = e0 + w * 2 + (l15 >> 3);
    const int node = members[e * MM + (l15 & 7)];
    const float* xrow = x + (long)node * DD + lg * 8;

    __syncthreads();   // B staged; no further barriers

    f32x4 acc[8];
#pragma unroll
    for (int i = 0; i < 8; i++) acc[i] = (f32x4){0.f, 0.f, 0.f, 0.f};
    bfrag shi[4], slo[4];   // S-half A-fragments for ks 4..7

#pragma unroll
    for (int ks = 0; ks < 4; ks++) {
        // load 8 features of this row: d = ks*32 + lg*8 + j
        const float4 a0 = *(const float4*)(xrow + ks * 32);
        const float4 a1 = *(const float4*)(xrow + ks * 32 + 4);
        float v[8] = {a0.x, a0.y, a0.z, a0.w, a1.x, a1.y, a1.z, a1.w};
        // sum over the 8 member rows (lanes differing in l15 bits 0..2)
        float s[8];
#pragma unroll
        for (int j = 0; j < 8; j++) s[j] = v[j];
#pragma unroll
        for (int mk = 1; mk <= 4; mk <<= 1)
#pragma unroll
            for (int j = 0; j < 8; j++) s[j] += __shfl_xor(s[j], mk);

        const int d0 = ks * 32 + lg * 8;
        {   // center: c = v - alpha*m ; repurpose s := m*(1-alpha)
            const float4 al0 = *(const float4*)(gn_alpha + d0);
            const float4 al1 = *(const float4*)(gn_alpha + d0 + 4);
            const float al[8] = {al0.x, al0.y, al0.z, al0.w, al1.x, al1.y, al1.z, al1.w};
#pragma unroll
            for (int j = 0; j < 8; j++) {
                const float m = s[j] * 0.125f;
                v[j] = v[j] - al[j] * m;
                s[j] = m * (1.0f - al[j]);
            }
        }
        float t2[8];
#pragma unroll
        for (int j = 0; j < 8; j++) t2[j] = v[j] * v[j];
#pragma unroll
        for (int mk = 1; mk <= 4; mk <<= 1)
#pragma unroll
            for (int j = 0; j < 8; j++) t2[j] += __shfl_xor(t2[j], mk);

        bfrag ahi, alo2;
        {
            const float4 g0 = *(const float4*)(gn_gamma + d0);
            const float4 g1 = *(const float4*)(gn_gamma + d0 + 4);
            const float4 b0 = *(const float4*)(gn_beta + d0);
            const float4 b1 = *(const float4*)(gn_beta + d0 + 4);
            const float gm[8] = {g0.x, g0.y, g0.z, g0.w, g1.x, g1.y, g1.z, g1.w};
            const float bt[8] = {b0.x, b0.y, b0.z, b0.w, b1.x, b1.y, b1.z, b1.w};
#pragma unroll
            for (int j = 0; j < 8; j++) {
                const float sc = gm[j] * rsqrtf(t2[j] * 0.125f + EPSV);
                const float nv = sc * v[j] + bt[j];
                short h, lo2; split1(nv, h, lo2);
                ahi[j] = h; alo2[j] = lo2;
                const float S = 8.0f * (sc * s[j] + bt[j]);
                short sh, sl; split1(S, sh, sl);
                shi[ks][j] = sh; slo[ks][j] = sl;
            }
        }

        const int sb = ks * 4 + lg;
#pragma unroll
        for (int nt = 0; nt < 8; nt++) {
            const int row = nt * 16 + l15;
            const int off = row * 256 + ((sb ^ (row & 7)) << 3);
            const bfrag bhi = *(const bfrag*)&bsh[0][off];
            const bfrag blo = *(const bfrag*)&bsh[1][off];
            acc[nt] = __builtin_amdgcn_mfma_f32_16x16x32_bf16(ahi, bhi, acc[nt], 0, 0, 0);
            acc[nt] = __builtin_amdgcn_mfma_f32_16x16x32_bf16(ahi, blo, acc[nt], 0, 0, 0);
            acc[nt] = __builtin_amdgcn_mfma_f32_16x16x32_bf16(alo2, bhi, acc[nt], 0, 0, 0);
        }
    }

    // S half of K (k = 128..255)
#pragma unroll
    for (int ks = 4; ks < 8; ks++) {
        const bfrag ahi = shi[ks - 4];
        const bfrag alo2 = slo[ks - 4];
        const int sb = ks * 4 + lg;
#pragma unroll
        for (int nt = 0; nt < 8; nt++) {
            const int row = nt * 16 + l15;
            const int off = row * 256 + ((sb ^ (row & 7)) << 3);
            const bfrag bhi = *(const bfrag*)&bsh[0][off];
            const bfrag blo = *(const bfrag*)&bsh[1][off];
            acc[nt] = __builtin_amdgcn_mfma_f32_16x16x32_bf16(ahi, bhi, acc[nt], 0, 0, 0);
            acc[nt] = __builtin_amdgcn_mfma_f32_16x16x32_bf16(ahi, blo, acc[nt], 0, 0, 0);
            acc[nt] = __builtin_amdgcn_mfma_f32_16x16x32_bf16(alo2, bhi, acc[nt], 0, 0, 0);
        }
    }

    // ---- epilogue: acc row = lg*4+q (rows 0-7 edge A via lg0/1, 8-15 edge B)
    float partial = 0.f;
#pragma unroll
    for (int nt = 0; nt < 8; nt++) {
        const int col = nt * 16 + l15;
        const float bias = cheb_b[col];
        float mx = -2.f, mn = 2.f, ssq = 0.f;
#pragma unroll
        for (int q = 0; q < 4; q++) {
            float h = acc[nt][q] + bias;
            h = fminf(1.0f, fmaxf(-1.0f, h));
            mx = fmaxf(mx, h); mn = fminf(mn, h); ssq += h * h;
        }
        mx = fmaxf(mx, __shfl_xor(mx, 16));
        mn = fminf(mn, __shfl_xor(mn, 16));
        ssq += __shfl_xor(ssq, 16);
        partial += (mx - mn) * lin_W[col] + sqrtf(ssq * 0.125f) * lin_W[DD + col];
    }
    if (lg & 1) partial = 0.f;
    partial += __shfl_xor(partial, 1);
    partial += __shfl_xor(partial, 2);
    partial += __shfl_xor(partial, 4);
    partial += __shfl_xor(partial, 8);
    if (l == 0 || l == 32) {
        const float z = partial + lin_b[0];
        out[e0 + w * 2 + (l >> 5)] = 1.0f / (1.0f + expf(-z));
    }
}

// ---------------------------------------------------------------------------
extern "C" void kernel_launch(void* const* d_in, const int* in_sizes, int n_in,
                              void* d_out, int out_size, void* d_ws, size_t ws_size,
                              hipStream_t stream) {
    const float* pos    = (const float*)d_in[0];
    const float* W_enc  = (const float*)d_in[1];
    const float* b_enc  = (const float*)d_in[2];
    const float* gammaP = (const float*)d_in[3];
    const float* betaP  = (const float*)d_in[4];
    const float* alphaP = (const float*)d_in[5];
    const float* cheb_W = (const float*)d_in[6];
    const float* cheb_b = (const float*)d_in[7];
    const float* lin_W  = (const float*)d_in[8];
    const float* lin_b  = (const float*)d_in[9];
    const int*   members = (const int*)d_in[10];
    // d_in[11] edge_index, d_in[12] batch: fixed 8-clique; unused.
    float* out = (float*)d_out;

    char* ws = (char*)d_ws;
    float* x = (float*)ws;                                         // 25,600,000 B
    unsigned short* WencT_hi = (unsigned short*)(ws + 25600000);   // 128*512
    unsigned short* WencT_lo = WencT_hi + DD * FF;
    unsigned short* WabT_hi  = WencT_lo + DD * FF;                 // 128*256
    unsigned short* WabT_lo  = WabT_hi + DD * 256;

    prep_kernel<<<256, 256, 0, stream>>>(W_enc, cheb_W, WencT_hi, WencT_lo, WabT_hi, WabT_lo);
    enc_kernel<<<(NN + 127) / 128, 512, 0, stream>>>(pos, WencT_hi, WencT_lo, b_enc, x);
    edge_kernel<<<EE / 32, 1024, 0, stream>>>(x, members, WabT_hi, WabT_lo,
                                              gammaP, betaP, alphaP, cheb_b, lin_W, lin_b, out);
}

// Round 3
// 262.496 us; speedup vs baseline: 1.7976x; 1.0153x over previous
//
#include <hip/hip_runtime.h>
#include <hip/hip_bf16.h>

// Problem constants (fixed by the reference)
#define NN   50000   // nodes
#define FF   512     // input features
#define DD   128     // embedding dim
#define CC   128     // conv channels
#define EE   20000   // hyperedges
#define MM   8       // nodes per hyperedge
#define EPSV 1e-5f

typedef __attribute__((ext_vector_type(8)))  short bfrag;   // 8 bf16 (4 VGPRs)
typedef __attribute__((ext_vector_type(16))) float f32x16;  // 32x32 MFMA accumulator

#define MFMA32(a, b, c) __builtin_amdgcn_mfma_f32_32x32x16_bf16((a), (b), (c), 0, 0, 0)

// fp32 -> bf16 bits, round-to-nearest-even
__device__ __forceinline__ unsigned short f2bf(float f) {
    unsigned u = __builtin_bit_cast(unsigned, f);
    unsigned r = u + 0x7FFFu + ((u >> 16) & 1u);
    return (unsigned short)(r >> 16);
}
__device__ __forceinline__ float bf2f(unsigned short h) {
    unsigned u = ((unsigned)h) << 16;
    return __builtin_bit_cast(float, u);
}
// split a into hi+lo bf16 (residual split: a ~= hi + lo, error ~2^-17 |a|)
__device__ __forceinline__ void split1(float a, short& hi, short& lo) {
    unsigned short h = f2bf(a);
    hi = (short)h;
    lo = (short)f2bf(a - bf2f(h));
}

// ---------------------------------------------------------------------------
// K0: prep — transposed, hi/lo-split bf16 weights (linear layout; consumers
// swizzle at LDS-write time).
//   WencT[n][k] = W_enc[k][n]                                (128 x 512)
//   WabT [c][k] : k<128 -> Wa[k][c], k>=128 -> Wb[k-128][c]  (128 x 256)
//   Wa = W0 + W1/7 - (47/49) W2 ;  Wb = -W1/7 + (12/49) W2
// ---------------------------------------------------------------------------
__global__ void prep_kernel(const float* __restrict__ W_enc,
                            const float* __restrict__ cheb_W,
                            unsigned short* __restrict__ WencT_hi,
                            unsigned short* __restrict__ WencT_lo,
                            unsigned short* __restrict__ WabT_hi,
                            unsigned short* __restrict__ WabT_lo) {
    int tid = blockIdx.x * blockDim.x + threadIdx.x;
    int stride = gridDim.x * blockDim.x;
    for (int idx = tid; idx < DD * FF; idx += stride) {
        int n = idx / FF, k = idx % FF;
        float v = W_enc[k * DD + n];
        short hi, lo; split1(v, hi, lo);
        WencT_hi[idx] = (unsigned short)hi;
        WencT_lo[idx] = (unsigned short)lo;
    }
    const float c1 = 1.0f / 7.0f;
    const float c2 = -47.0f / 49.0f;
    const float c3 = -1.0f / 7.0f;
    const float c4 = 12.0f / 49.0f;
    for (int idx = tid; idx < DD * 256; idx += stride) {
        int c = idx / 256, k = idx % 256;
        float v;
        if (k < DD) {
            v = cheb_W[0 * DD * CC + k * CC + c]
              + c1 * cheb_W[1 * DD * CC + k * CC + c]
              + c2 * cheb_W[2 * DD * CC + k * CC + c];
        } else {
            int d = k - DD;
            v = c3 * cheb_W[1 * DD * CC + d * CC + c]
              + c4 * cheb_W[2 * DD * CC + d * CC + c];
        }
        short hi, lo; split1(v, hi, lo);
        WabT_hi[idx] = (unsigned short)hi;
        WabT_lo[idx] = (unsigned short)lo;
    }
}

// ---------------------------------------------------------------------------
// K1: encoder GEMM  x = clip(pos @ W_enc + b_enc, -1, 1)   [50000,128] fp32
// 512 thr = 8 waves (2m x 4n), BM=64, wave tile 32x32, K in 8 phases of 64.
// A staged via LDS (coalesced 256B/row global reads, hi/lo split at stage),
// B hi/lo staged per phase. LDS 48KB -> 3 blocks/CU (75% occ). Grid 782.
// ---------------------------------------------------------------------------
__global__ __launch_bounds__(512, 6) void enc_kernel(
        const float* __restrict__ pos,
        const unsigned short* __restrict__ BT_hi,
        const unsigned short* __restrict__ BT_lo,
        const float* __restrict__ b_enc,
        float* __restrict__ x) {
    __shared__ unsigned short ahz[2][64 * 64];    // A hi/lo, 16 KB
    __shared__ unsigned short bhz[2][128 * 64];   // B hi/lo, 32 KB

    const int t = threadIdx.x;
    const int w = t >> 6, l = t & 63, l31 = l & 31, lg2 = l >> 5;
    const int wm = w & 1, wn = w >> 1;            // 2 m-tiles x 4 n-tiles

    f32x16 acc;
#pragma unroll
    for (int i = 0; i < 16; i++) acc[i] = 0.f;

    for (int ph = 0; ph < 8; ph++) {
        if (ph) __syncthreads();
        // ---- stage A: 64 rows x 64 k fp32, thread t -> row t>>3, 32B chunk
        {
            const int r = t >> 3, c8 = t & 7;
            int grow = blockIdx.x * 64 + r;
            if (grow >= NN) grow = NN - 1;
            const float* src = pos + (size_t)grow * FF + ph * 64 + c8 * 8;
            const float4 v0 = *(const float4*)src;
            const float4 v1 = *(const float4*)(src + 4);
            const float av[8] = {v0.x, v0.y, v0.z, v0.w, v1.x, v1.y, v1.z, v1.w};
            bfrag hi, lo;
#pragma unroll
            for (int j = 0; j < 8; j++) { short h, lo2; split1(av[j], h, lo2); hi[j] = h; lo[j] = lo2; }
            const int dst = r * 64 + ((c8 ^ (r & 7)) << 3);
            *(bfrag*)&ahz[0][dst] = hi;
            *(bfrag*)&ahz[1][dst] = lo;
        }
        // ---- stage B: 2 arrays x 128 n x 8 slots of 16B
#pragma unroll
        for (int i = 0; i < 4; i++) {
            const int c = t + i * 512;
            const int arr = c >> 10, rc = c & 1023, n = rc >> 3, slot = rc & 7;
            const unsigned short* src = (arr ? BT_lo : BT_hi) + (size_t)n * FF + ph * 64 + slot * 8;
            *(bfrag*)&bhz[arr][n * 64 + ((slot ^ (n & 7)) << 3)] = *(const bfrag*)src;
        }
        __syncthreads();
        // ---- compute: 4 k-steps of 16
#pragma unroll
        for (int ks = 0; ks < 4; ks++) {
            const int slot = ks * 2 + lg2;
            const int arow = wm * 32 + l31;
            const int aoff = arow * 64 + ((slot ^ (arow & 7)) << 3);
            const bfrag ahi = *(const bfrag*)&ahz[0][aoff];
            const bfrag alo = *(const bfrag*)&ahz[1][aoff];
            const int col = wn * 32 + l31;
            const int boff = col * 64 + ((slot ^ (col & 7)) << 3);
            const bfrag bhi = *(const bfrag*)&bhz[0][boff];
            const bfrag blo = *(const bfrag*)&bhz[1][boff];
            acc = MFMA32(ahi, bhi, acc);
            acc = MFMA32(ahi, blo, acc);
            acc = MFMA32(alo, bhi, acc);
        }
    }

    // ---- epilogue: C/D col = lane&31, row = (r&3) + 8*(r>>2) + 4*lg2
    const int col = wn * 32 + l31;
    const float bias = b_enc[col];
    const int brow = blockIdx.x * 64 + wm * 32;
#pragma unroll
    for (int r = 0; r < 16; r++) {
        const int row = brow + (r & 3) + 8 * (r >> 2) + 4 * lg2;
        if (row < NN) {
            float v = acc[r] + bias;
            x[(size_t)row * DD + col] = fminf(1.0f, fmaxf(-1.0f, v));
        }
    }
}

// ---------------------------------------------------------------------------
// K2: fused edge kernel. 512 thr = 8 waves, 4 edges/wave (32-row m-tile),
// 32 edges/block, grid 625. GraphNorm in registers (shfl over 8 members);
// S colsum closed-form, S-MFMAs interleaved (no fragment arrays -> no spill).
// LDS: Wa-hi + Wb-hi (64 KB, XOR-swizzled) -> 2 blocks/CU. Wa-lo frags from
// global (L2-hot) keep the 3-pass split on the norm half; S half 1-pass.
// ---------------------------------------------------------------------------
__global__ __launch_bounds__(512, 4) void edge_kernel(
        const float* __restrict__ x,
        const int* __restrict__ members,
        const unsigned short* __restrict__ WabT_hi,
        const unsigned short* __restrict__ WabT_lo,
        const float* __restrict__ gn_gamma,
        const float* __restrict__ gn_beta,
        const float* __restrict__ gn_alpha,
        const float* __restrict__ cheb_b,
        const float* __restrict__ lin_W,
        const float* __restrict__ lin_b,
        float* __restrict__ out) {
    __shared__ unsigned short wa_hi[128 * 128];   // 32 KB
    __shared__ unsigned short wb_hi[128 * 128];   // 32 KB

    const int t = threadIdx.x;
    const int w = t >> 6, l = t & 63, l31 = l & 31, lg2 = l >> 5;

    // ---- stage B (hi arrays only): 4096 16B chunks over 512 threads
#pragma unroll
    for (int i = 0; i < 8; i++) {
        const int c = t + i * 512;
        const int arr = c >> 11, rc = c & 2047, col = rc >> 4, slot = rc & 15;
        const bfrag v = *(const bfrag*)(WabT_hi + (size_t)col * 256 + arr * 128 + slot * 8);
        unsigned short* dst = arr ? wb_hi : wa_hi;
        *(bfrag*)&dst[col * 128 + ((slot ^ (col & 15)) << 3)] = v;
    }

    // wave's 4 edges: lane row l31 -> edge l31>>3, member l31&7
    const int node = members[blockIdx.x * 256 + w * 32 + l31];
    const float* xrow = x + (size_t)node * DD;

    __syncthreads();   // B staged; no further barriers

    f32x16 acc[4];
#pragma unroll
    for (int nt = 0; nt < 4; nt++)
#pragma unroll
        for (int i = 0; i < 16; i++) acc[nt][i] = 0.f;

#pragma unroll
    for (int ks = 0; ks < 8; ks++) {
        const int koff = ks * 16 + lg2 * 8;      // d-chunk 0..127
        const float4 a0 = *(const float4*)(xrow + koff);
        const float4 a1 = *(const float4*)(xrow + koff + 4);
        float v[8] = {a0.x, a0.y, a0.z, a0.w, a1.x, a1.y, a1.z, a1.w};
        float s[8];
#pragma unroll
        for (int j = 0; j < 8; j++) s[j] = v[j];
#pragma unroll
        for (int mk = 1; mk <= 4; mk <<= 1)
#pragma unroll
            for (int j = 0; j < 8; j++) s[j] += __shfl_xor(s[j], mk);

        {   // center: c = v - alpha*m ; repurpose s := m*(1-alpha)
            const float4 al0 = *(const float4*)(gn_alpha + koff);
            const float4 al1 = *(const float4*)(gn_alpha + koff + 4);
            const float al[8] = {al0.x, al0.y, al0.z, al0.w, al1.x, al1.y, al1.z, al1.w};
#pragma unroll
            for (int j = 0; j < 8; j++) {
                const float m = s[j] * 0.125f;
                v[j] = v[j] - al[j] * m;
                s[j] = m * (1.0f - al[j]);
            }
        }
        float t2[8];
#pragma unroll
        for (int j = 0; j < 8; j++) t2[j] = v[j] * v[j];
#pragma unroll
        for (int mk = 1; mk <= 4; mk <<= 1)
#pragma unroll
            for (int j = 0; j < 8; j++) t2[j] += __shfl_xor(t2[j], mk);

        bfrag ahi, alo, shi;
        {
            const float4 g0 = *(const float4*)(gn_gamma + koff);
            const float4 g1 = *(const float4*)(gn_gamma + koff + 4);
            const float4 b0 = *(const float4*)(gn_beta + koff);
            const float4 b1 = *(const float4*)(gn_beta + koff + 4);
            const float gm[8] = {g0.x, g0.y, g0.z, g0.w, g1.x, g1.y, g1.z, g1.w};
            const float bt[8] = {b0.x, b0.y, b0.z, b0.w, b1.x, b1.y, b1.z, b1.w};
#pragma unroll
            for (int j = 0; j < 8; j++) {
                const float sc = gm[j] * rsqrtf(t2[j] * 0.125f + EPSV);
                const float nv = sc * v[j] + bt[j];
                short h, lo2; split1(nv, h, lo2);
                ahi[j] = h; alo[j] = lo2;
                const float S = 8.0f * (sc * s[j] + bt[j]);
                shi[j] = (short)f2bf(S);
            }
        }

        const int slot = ks * 2 + lg2;           // 0..15
#pragma unroll
        for (int nt = 0; nt < 4; nt++) {
            const int col = nt * 32 + l31;
            const int woff = col * 128 + ((slot ^ (col & 15)) << 3);
            const bfrag wahi = *(const bfrag*)&wa_hi[woff];
            const bfrag wbh  = *(const bfrag*)&wb_hi[woff];
            const bfrag walo = *(const bfrag*)(WabT_lo + (size_t)col * 256 + koff);
            acc[nt] = MFMA32(ahi, wahi, acc[nt]);
            acc[nt] = MFMA32(ahi, walo, acc[nt]);
            acc[nt] = MFMA32(alo, wahi, acc[nt]);
            acc[nt] = MFMA32(shi, wbh,  acc[nt]);
        }
    }

    // ---- epilogue: reg r of acc[nt]: edge e = r>>2, member-row (r&3)+4*lg2,
    // col = nt*32 + l31. Pool 8 member rows = 4 regs + shfl_xor(32).
    float p[4] = {0.f, 0.f, 0.f, 0.f};
#pragma unroll
    for (int nt = 0; nt < 4; nt++) {
        const int col = nt * 32 + l31;
        const float bias = cheb_b[col];
        const float w1 = lin_W[col], w2 = lin_W[DD + col];
#pragma unroll
        for (int e = 0; e < 4; e++) {
            float mx = -2.f, mn = 2.f, ssq = 0.f;
#pragma unroll
            for (int q = 0; q < 4; q++) {
                float h = acc[nt][e * 4 + q] + bias;
                h = fminf(1.0f, fmaxf(-1.0f, h));
                mx = fmaxf(mx, h); mn = fminf(mn, h); ssq += h * h;
            }
            mx = fmaxf(mx, __shfl_xor(mx, 32));
            mn = fminf(mn, __shfl_xor(mn, 32));
            ssq += __shfl_xor(ssq, 32);
            p[e] += (mx - mn) * w1 + sqrtf(ssq * 0.125f) * w2;
        }
    }
#pragma unroll
    for (int mk = 1; mk <= 16; mk <<= 1)
#pragma unroll
        for (int e = 0; e < 4; e++) p[e] += __shfl_xor(p[e], mk);
    if (l == 0) {
        const float b0 = lin_b[0];
#pragma unroll
        for (int e = 0; e < 4; e++) {
            const float z = p[e] + b0;
            out[blockIdx.x * 32 + w * 4 + e] = 1.0f / (1.0f + expf(-z));
        }
    }
}

// ---------------------------------------------------------------------------
extern "C" void kernel_launch(void* const* d_in, const int* in_sizes, int n_in,
                              void* d_out, int out_size, void* d_ws, size_t ws_size,
                              hipStream_t stream) {
    const float* pos    = (const float*)d_in[0];
    const float* W_enc  = (const float*)d_in[1];
    const float* b_enc  = (const float*)d_in[2];
    const float* gammaP = (const float*)d_in[3];
    const float* betaP  = (const float*)d_in[4];
    const float* alphaP = (const float*)d_in[5];
    const float* cheb_W = (const float*)d_in[6];
    const float* cheb_b = (const float*)d_in[7];
    const float* lin_W  = (const float*)d_in[8];
    const float* lin_b  = (const float*)d_in[9];
    const int*   members = (const int*)d_in[10];
    // d_in[11] edge_index, d_in[12] batch: fixed 8-clique; unused.
    float* out = (float*)d_out;

    char* ws = (char*)d_ws;
    float* x = (float*)ws;                                         // 25,600,000 B
    unsigned short* WencT_hi = (unsigned short*)(ws + 25600000);   // 128*512
    unsigned short* WencT_lo = WencT_hi + DD * FF;
    unsigned short* WabT_hi  = WencT_lo + DD * FF;                 // 128*256
    unsigned short* WabT_lo  = WabT_hi + DD * 256;

    prep_kernel<<<256, 256, 0, stream>>>(W_enc, cheb_W, WencT_hi, WencT_lo, WabT_hi, WabT_lo);
    enc_kernel<<<(NN + 63) / 64, 512, 0, stream>>>(pos, WencT_hi, WencT_lo, b_enc, x);
    edge_kernel<<<EE / 32, 512, 0, stream>>>(x, members, WabT_hi, WabT_lo,
                                             gammaP, betaP, alphaP, cheb_b, lin_W, lin_b, out);
}